// Round 1
// baseline (721.636 us; speedup 1.0000x reference)
//
#include <hip/hip_runtime.h>
#include <stdint.h>

#define E_EDGES 262144
#define TILE_M 128
#define MAX_TILES 2064

typedef unsigned short ushort_t;
typedef __attribute__((ext_vector_type(8))) short short8;
typedef __attribute__((ext_vector_type(4))) float f32x4;

// ---- workspace layout (bytes) ----
#define OFF_WT   0                              // bf16 Wt[n=256][k=512] (transposed combined W1;W2)
#define OFF_WP   (512*256*2)                    // 262144: bf16 W_pred frags [16][8][64][8]
#define OFF_PERM (OFF_WP + 16*8*64*8*2)         // 393216: int perm[MAX_TILES*128]
#define OFF_HIST (OFF_PERM + MAX_TILES*128*4)   // 1449984: int[16]
#define OFF_SEG  (OFF_HIST + 64)                // int[17]
#define OFF_CUR  (OFF_SEG + 128)                // int[16]
#define OFF_SUMS (OFF_CUR + 64)                 // float[16]

__device__ __forceinline__ ushort_t f2bf(float f) {
  union { float f; unsigned u; } c; c.f = f;
  unsigned r = c.u + 0x7fffu + ((c.u >> 16) & 1u);   // RNE, finite inputs
  return (ushort_t)(r >> 16);
}

__device__ __forceinline__ void async_copy16(void* lds, const void* g) {
  __builtin_amdgcn_global_load_lds(
      (const __attribute__((address_space(1))) unsigned int*)g,
      (__attribute__((address_space(3))) unsigned int*)lds, 16, 0, 0);
}

// ---- prologue: init perm=-1, build bf16 Wt (transposed), W_pred fragment layout, zero accums ----
__global__ __launch_bounds__(256) void prep_k(const float* __restrict__ W1,
    const float* __restrict__ W2, const float* __restrict__ Wp,
    char* __restrict__ ws) {
  const int i = blockIdx.x * 256 + threadIdx.x;
  int* perm = (int*)(ws + OFF_PERM);
  if (i < MAX_TILES * 128) perm[i] = -1;
  if (i < 512 * 256) {            // Wt[n][k] = (k<256 ? W1[k][n] : W2[k-256][n])
    ushort_t* Wt = (ushort_t*)(ws + OFF_WT);
    const int n = i >> 9, k = i & 511;
    const float v = (k < 256) ? W1[(k << 8) + n] : W2[((k - 256) << 8) + n];
    Wt[i] = f2bf(v);
  }
  if (i < 16 * 8 * 64 * 8) {      // Wp frag: [pair][s][lane][j] = W_pred[pair][32s+8*(lane>>4)+j][lane&15]
    ushort_t* Wpf = (ushort_t*)(ws + OFF_WP);
    const int j = i & 7, l = (i >> 3) & 63, s = (i >> 9) & 7, p = i >> 12;
    const int k = s * 32 + (l >> 4) * 8 + j, c = l & 15;
    Wpf[i] = f2bf(Wp[((p << 8) + k) * 16 + c]);
  }
  if (i < 16) {
    ((int*)(ws + OFF_HIST))[i] = 0;
    ((int*)(ws + OFF_CUR))[i] = 0;
    ((float*)(ws + OFF_SUMS))[i] = 0.f;
  }
}

__global__ __launch_bounds__(256) void hist_k(const int* __restrict__ st,
    const int* __restrict__ dt, char* __restrict__ ws) {
  __shared__ int lh[16];
  int* hist = (int*)(ws + OFF_HIST);
  const int t = threadIdx.x;
  if (t < 16) lh[t] = 0;
  __syncthreads();
  const int i = blockIdx.x * 256 + t;
  if (i < E_EDGES) atomicAdd(&lh[st[i] * 4 + dt[i]], 1);
  __syncthreads();
  if (t < 16 && lh[t] > 0) atomicAdd(&hist[t], lh[t]);
}

__global__ void scan_k(char* __restrict__ ws) {
  if (threadIdx.x == 0) {
    const int* hist = (const int*)(ws + OFF_HIST);
    int* seg = (int*)(ws + OFF_SEG);
    int acc = 0;
    for (int p = 0; p < 16; ++p) {
      seg[p] = acc;
      acc += (hist[p] + 127) & ~127;   // 128-aligned padded segments
    }
    seg[16] = acc;
  }
}

__global__ __launch_bounds__(256) void scatter_k(const int* __restrict__ st,
    const int* __restrict__ dt, char* __restrict__ ws) {
  __shared__ int lh[16], lbase[16];
  const int* seg = (const int*)(ws + OFF_SEG);
  int* cur = (int*)(ws + OFF_CUR);
  int* perm = (int*)(ws + OFF_PERM);
  const int t = threadIdx.x;
  if (t < 16) lh[t] = 0;
  __syncthreads();
  const int i = blockIdx.x * 256 + t;
  int p = 0, r = 0;
  const bool v = (i < E_EDGES);
  if (v) { p = st[i] * 4 + dt[i]; r = atomicAdd(&lh[p], 1); }
  __syncthreads();
  if (t < 16 && lh[t] > 0) lbase[t] = atomicAdd(&cur[t], lh[t]);
  __syncthreads();
  if (v) perm[seg[p] + lbase[p] + r] = i;
}

// ---- fused: gather+GEMM1(bf16 MFMA, K=512) -> relu -> GEMM2 head -> softmax-CE -> per-pair sums ----
__global__ __launch_bounds__(512) void main_k(
    const float* __restrict__ h_src, const float* __restrict__ h_dst,
    const float* __restrict__ b_dec, const float* __restrict__ b_pred,
    const int* __restrict__ etc_arr, const int* __restrict__ emap,
    char* __restrict__ ws) {
  const ushort_t* Wt = (const ushort_t*)(ws + OFF_WT);
  const short8* Wpf = (const short8*)(ws + OFF_WP);
  const int* perm = (const int*)(ws + OFF_PERM);
  const int* seg = (const int*)(ws + OFF_SEG);
  float* sums = (float*)(ws + OFF_SUMS);

  const int tb = blockIdx.x * TILE_M;
  if (tb >= seg[16]) return;          // beyond padded total: whole block exits
  int pair = 0;
#pragma unroll
  for (int p = 1; p < 16; ++p) pair += (tb >= seg[p]) ? 1 : 0;

  __shared__ __align__(16) char smem[65536];
  ushort_t* A_ls = (ushort_t*)smem;   // [128][72] bf16 (padded, 144B rows: 16B-aligned, 2-way banks = free)
  char* B_ls = smem + 18432;          // 32 fragment-order chunks * 1KB
  ushort_t* H_ls = (ushort_t*)smem;   // [128][256] bf16, reuses staging after K-loop

  const int t = threadIdx.x;
  const int w = t >> 6, lane = t & 63;
  const int quad = lane >> 4, l15 = lane & 15;
  const int wm = w >> 2, wn = w & 3;  // wave tile: rows 64*wm, cols 64*wn

  const int arow = t >> 2, acg = t & 3;
  const int e_stage = perm[tb + arow];

  const f32x4 zero4 = {0.f, 0.f, 0.f, 0.f};
  f32x4 acc[4][4];
#pragma unroll
  for (int i = 0; i < 4; ++i)
#pragma unroll
    for (int j = 0; j < 4; ++j) acc[i][j] = zero4;

  for (int kt = 0; kt < 8; ++kt) {
    // stage A: gathered edge rows, fp32 -> bf16
    const float* srcb = (kt < 4) ? h_src : h_dst;
    const int kofs = (kt & 3) * 64 + acg * 16;
    f32x4 fv[4];
    if (e_stage >= 0) {
      const f32x4* gp = (const f32x4*)(srcb + ((size_t)e_stage << 8) + kofs);
#pragma unroll
      for (int q = 0; q < 4; ++q) fv[q] = gp[q];
    } else {
#pragma unroll
      for (int q = 0; q < 4; ++q) fv[q] = zero4;
    }
    union { ushort_t u[16]; short8 v[2]; } pk;
#pragma unroll
    for (int q = 0; q < 4; ++q)
#pragma unroll
      for (int x = 0; x < 4; ++x) pk.u[q * 4 + x] = f2bf(fv[q][x]);
    {
      ushort_t* dst = A_ls + arow * 72 + acg * 16;
      *(short8*)dst = pk.v[0];
      *(short8*)(dst + 8) = pk.v[1];
    }
    // stage B: async global->LDS, fragment order (conflict-free b128 reads)
#pragma unroll
    for (int ci = 0; ci < 4; ++ci) {
      const int chunk = w * 4 + ci;
      const int ks = chunk >> 4, nt = chunk & 15;
      const int n = nt * 16 + l15;
      const int k = kt * 64 + ks * 32 + quad * 8;
      async_copy16(B_ls + chunk * 1024, Wt + n * 512 + k);
    }
    __syncthreads();
#pragma unroll
    for (int ks = 0; ks < 2; ++ks) {
      short8 a[4], b[4];
#pragma unroll
      for (int i = 0; i < 4; ++i)
        a[i] = *(const short8*)(A_ls + (wm * 64 + i * 16 + l15) * 72 + ks * 32 + quad * 8);
#pragma unroll
      for (int j = 0; j < 4; ++j)
        b[j] = *(const short8*)(B_ls + (ks * 16 + wn * 4 + j) * 1024 + lane * 16);
#pragma unroll
      for (int i = 0; i < 4; ++i)
#pragma unroll
        for (int j = 0; j < 4; ++j)
          acc[i][j] = __builtin_amdgcn_mfma_f32_16x16x32_bf16(a[i], b[j], acc[i][j], 0, 0, 0);
    }
    __syncthreads();
  }

  // epilogue GEMM1: bias + relu, C-layout (col=lane&15, row=quad*4+reg) -> H_ls bf16
  float bj[4];
#pragma unroll
  for (int j = 0; j < 4; ++j) bj[j] = b_dec[wn * 64 + j * 16 + l15];
#pragma unroll
  for (int i = 0; i < 4; ++i)
#pragma unroll
    for (int j = 0; j < 4; ++j)
#pragma unroll
      for (int r = 0; r < 4; ++r) {
        const int row = wm * 64 + i * 16 + quad * 4 + r;
        const int col = wn * 64 + j * 16 + l15;
        float v = acc[i][j][r] + bj[j];
        v = fmaxf(v, 0.f);
        H_ls[row * 256 + col] = f2bf(v);
      }
  __syncthreads();

  // GEMM2: wave w handles 16 rows; logits[16x16] over K=256
  f32x4 acc2 = zero4;
#pragma unroll
  for (int s = 0; s < 8; ++s) {
    short8 a = *(const short8*)(H_ls + (w * 16 + l15) * 256 + s * 32 + quad * 8);
    short8 b = Wpf[(pair * 8 + s) * 64 + lane];
    acc2 = __builtin_amdgcn_mfma_f32_16x16x32_bf16(a, b, acc2, 0, 0, 0);
  }

  // loss: 16-lane-group softmax-CE (col = lane&15 = class), accumulate per-pair
  const float bp = b_pred[pair * 16 + l15];
  float wacc = 0.f;
#pragma unroll
  for (int r = 0; r < 4; ++r) {
    const int row = w * 16 + quad * 4 + r;
    const int e = perm[tb + row];
    float v = acc2[r] + bp;
    float m = v;
#pragma unroll
    for (int o = 1; o < 16; o <<= 1) m = fmaxf(m, __shfl_xor(m, o, 16));
    float sm = __expf(v - m);
#pragma unroll
    for (int o = 1; o < 16; o <<= 1) sm += __shfl_xor(sm, o, 16);
    int label = 0;
    if (e >= 0) label = emap[pair * 24 + etc_arr[e]];
    const float vlab = __shfl(v, (lane & 48) + label, 64);
    if (e >= 0 && l15 == 0) wacc += m + __logf(sm) - vlab;
  }
  wacc += __shfl_xor(wacc, 16, 64);
  wacc += __shfl_xor(wacc, 32, 64);
  if (lane == 0) atomicAdd(&sums[pair], wacc);
}

__global__ void finalize_k(const char* __restrict__ ws, float* __restrict__ out) {
  const float* sums = (const float*)(ws + OFF_SUMS);
  const int* hist = (const int*)(ws + OFF_HIST);
  const int t = threadIdx.x;
  float g = 0.f, pr = 0.f;
  if (t < 16) {
    const int c = hist[t];
    if (c > 0) { g = sums[t] / (float)c; pr = 1.f; }
  }
#pragma unroll
  for (int o = 1; o < 16; o <<= 1) { g += __shfl_xor(g, o, 64); pr += __shfl_xor(pr, o, 64); }
  if (t == 0) out[0] = g / pr;
}

extern "C" void kernel_launch(void* const* d_in, const int* in_sizes, int n_in,
                              void* d_out, int out_size, void* d_ws, size_t ws_size,
                              hipStream_t stream) {
  const float* h_src  = (const float*)d_in[0];
  const float* h_dst  = (const float*)d_in[1];
  const float* W1     = (const float*)d_in[2];
  const float* W2     = (const float*)d_in[3];
  const float* b_dec  = (const float*)d_in[4];
  const float* W_pred = (const float*)d_in[5];
  const float* b_pred = (const float*)d_in[6];
  const int* st   = (const int*)d_in[7];
  const int* dt   = (const int*)d_in[8];
  const int* etc  = (const int*)d_in[9];
  const int* emap = (const int*)d_in[10];
  char* ws = (char*)d_ws;
  float* out = (float*)d_out;

  prep_k<<<(MAX_TILES * 128 + 255) / 256, 256, 0, stream>>>(W1, W2, W_pred, ws);
  hist_k<<<E_EDGES / 256, 256, 0, stream>>>(st, dt, ws);
  scan_k<<<1, 64, 0, stream>>>(ws);
  scatter_k<<<E_EDGES / 256, 256, 0, stream>>>(st, dt, ws);
  main_k<<<MAX_TILES, 512, 0, stream>>>(h_src, h_dst, b_dec, b_pred, etc, emap, ws);
  finalize_k<<<1, 64, 0, stream>>>(ws, out);
}